// Round 2
// baseline (81539.069 us; speedup 1.0000x reference)
//
#include <hip/hip_runtime.h>
#include <cstddef>

// Decoder: B=64, T=512, I=512, H1=256, H2=128, C=1024, M=80, L=2
// Round 7: persistent cooperative kernel WITHOUT global fences.
//   Round-6 post-mortem: __threadfence() in gsync = buffer_inv sc1 -> whole
//   per-XCD L2 invalidated 2048x -> 27 MB/step weight refetch at 284 GB/s
//   (FETCH_SIZE 13.85 GB/dispatch) = 95 us/step. Fix: weights stay plain
//   (L2-resident); ONLY cross-XCD state (xcat*, pproj, barrier) goes through
//   agent-scope relaxed atomics (sc1: write-through to IF, reads bypass L2).
//   f32 h-state is block-local -> plain. Barrier: per-XCD-sharded counters,
//   RELEASE add (wbl2 writeback, no invalidate) + relaxed poll.

namespace {

constexpr int kB = 64, kT = 512, kI = 512, kH1 = 256, kH2 = 128, kC = 1024, kM = 80;
constexpr size_t X0 = (size_t)kB * 1664;
constexpr size_t XC = (size_t)kB * 2048;
constexpr size_t HB = (size_t)kC * kB;

typedef __attribute__((ext_vector_type(8))) __bf16 bf16x8;
typedef __attribute__((ext_vector_type(4))) float f32x4;

__device__ __forceinline__ float sigm(float x) { return 1.0f / (1.0f + __expf(-x)); }
__device__ __forceinline__ float tanh_(float x) {
  float a = fabsf(x);
  float e = __expf(-2.0f * a);
  float r = (1.0f - e) / (1.0f + e);
  return copysignf(r, x);
}
__device__ __forceinline__ unsigned short f2bf(float x) {
  unsigned u = __builtin_bit_cast(unsigned, x);
  u += 0x7fffu + ((u >> 16) & 1u);   // RNE
  return (unsigned short)(u >> 16);
}
__device__ __forceinline__ bf16x8 asbf(uint4 v) { return __builtin_bit_cast(bf16x8, v); }
__device__ __forceinline__ f32x4 mfma16(bf16x8 a, bf16x8 b, f32x4 c) {
  return __builtin_amdgcn_mfma_f32_16x16x32_bf16(a, b, c, 0, 0, 0);
}

// ---- agent-scope (cross-XCD coherent) access helpers ----------------------
__device__ __forceinline__ unsigned long long ld64_coh(const void* p) {
  return __hip_atomic_load((unsigned long long*)p, __ATOMIC_RELAXED, __HIP_MEMORY_SCOPE_AGENT);
}
__device__ __forceinline__ void st64_coh(void* p, unsigned long long v) {
  __hip_atomic_store((unsigned long long*)p, v, __ATOMIC_RELAXED, __HIP_MEMORY_SCOPE_AGENT);
}
__device__ __forceinline__ void st32_coh(void* p, unsigned v) {
  __hip_atomic_store((unsigned*)p, v, __ATOMIC_RELAXED, __HIP_MEMORY_SCOPE_AGENT);
}
__device__ __forceinline__ float ldf_coh(const float* p) {
  return __hip_atomic_load((float*)p, __ATOMIC_RELAXED, __HIP_MEMORY_SCOPE_AGENT);
}
__device__ __forceinline__ void stf_coh(float* p, float v) {
  __hip_atomic_store(p, v, __ATOMIC_RELAXED, __HIP_MEMORY_SCOPE_AGENT);
}
__device__ __forceinline__ unsigned long long pack4(unsigned a, unsigned b,
                                                    unsigned c, unsigned d) {
  return (unsigned long long)(a & 0xffffu)
       | ((unsigned long long)(b & 0xffffu) << 16)
       | ((unsigned long long)(c & 0xffffu) << 32)
       | ((unsigned long long)(d & 0xffffu) << 48);
}

// ---- weight repack: fp32 [row][col] -> bf16 frag order [rt][ks][lane][8] ----
__global__ __launch_bounds__(256) void k_build_frags(
    const float* __restrict__ srcA, int ldA,
    const float* __restrict__ srcB, int ldB,
    int row0, int K1, int nks, int nrt, unsigned short* __restrict__ dst) {
  int idx = blockIdx.x * 256 + threadIdx.x;
  int lane = idx & 63;
  int ks = (idx >> 6) % nks;
  int rt = idx / (64 * nks);
  if (rt >= nrt) return;
  int row = row0 + rt * 16 + (lane & 15);
  int kk = ks * 32 + ((lane >> 4) & 3) * 8;
  const float* s = (kk < K1) ? (srcA + (size_t)row * ldA + kk)
                             : (srcB + (size_t)row * ldB + (kk - K1));
  unsigned short* d = dst + ((size_t)(rt * nks + ks) * 64 + lane) * 8;
#pragma unroll
  for (int j = 0; j < 8; ++j) d[j] = f2bf(s[j]);
}

__global__ __launch_bounds__(256) void k_transpose(const float* __restrict__ src,
    int R, int Ccols, float* __restrict__ dst) {
  int i = blockIdx.x * 256 + threadIdx.x;
  if (i >= R * Ccols) return;
  int r = i / Ccols, c = i % Ccols;
  dst[c * R + r] = src[r * Ccols + c];
}

// ---- persistent-kernel parameter block ------------------------------------
struct KParams {
  const float* inputs;
  const float* proj_b;
  const float* w0t;
  const float* pre_b0;
  const float* w1t;
  const float* pre_b1;
  const unsigned short* Aat0; const unsigned short* Aat1; const unsigned short* Aat2;
  const unsigned short* Ar00; const unsigned short* Ar01; const unsigned short* Ar02;
  const unsigned short* Ar10; const unsigned short* Ar11; const unsigned short* Ar12;
  const float* attn_bih; const float* attn_bhh;
  const float* g_bih0; const float* g_bhh0;
  const float* g_bih1; const float* g_bhh1;
  const float* proj_w;
  unsigned short* xcat0; unsigned short* xcat1; unsigned short* xcat2;
  float* hA; float* h1; float* h2; float* x1; float* pproj; float* out;
  unsigned* bar;   // 8 counters, 128B apart
};

// ---- grid barrier: per-XCD-sharded counters, no L2 invalidation -----------
// Arrival: __syncthreads() drains vmcnt (sc1 write-throughs have reached the
// coherence point), then RELEASE fetch_add (buffer_wbl2 writeback of any dirty
// lines, NO invalidate -> weights stay L2-resident). Wait: relaxed sc1 polls.
__device__ __forceinline__ void gsync(unsigned* bar, unsigned target) {
  __syncthreads();
  if (threadIdx.x == 0) {
    __hip_atomic_fetch_add(&bar[(blockIdx.x & 7) * 32], 1u,
                           __ATOMIC_RELEASE, __HIP_MEMORY_SCOPE_AGENT);
  }
  if (threadIdx.x < 8) {
    while (__hip_atomic_load(&bar[threadIdx.x * 32], __ATOMIC_RELAXED,
                             __HIP_MEMORY_SCOPE_AGENT) < target)
      __builtin_amdgcn_s_sleep(2);
  }
  __syncthreads();
}

// ---- prenet phase (blocks 0..63, 512 threads) -----------------------------
__device__ __forceinline__ void prenet_phase(const KParams& p, int t, float* smem) {
  float* sfr  = smem;          // 80 (pad 96)
  float* sh   = smem + 96;     // 256
  float* sred = smem + 384;    // 160
  float* sp   = smem + 544;    // 128
  int b = blockIdx.x, tid = threadIdx.x;
  const float* feat = p.inputs + ((size_t)b * kT + t) * kI;
  unsigned short* dst = p.xcat0 + (size_t)(t & 1) * X0 + (size_t)b * 1664;
  if (tid < 256) {
    float2 fv = *(const float2*)(feat + tid * 2);
    unsigned pk = (unsigned)f2bf(fv.x) | ((unsigned)f2bf(fv.y) << 16);
    st32_coh((unsigned*)dst + tid, pk);
  }
  if (t > 0) {
    if (tid < 160) {
      int m = tid >> 1, half = tid & 1;
      const float* pp = p.pproj + ((size_t)(half * 32) * kM + m) * kB + b;
      float s = 0.0f;
#pragma unroll 8
      for (int r = 0; r < 32; ++r) s += ldf_coh(pp + (size_t)r * kM * kB);
      sred[tid] = s;
    }
    __syncthreads();
    if (tid < kM) {
      float f = p.proj_b[tid] + sred[tid * 2] + sred[tid * 2 + 1];
      sfr[tid] = f;
      p.out[(size_t)b * kT * kM + (size_t)(t - 1) * kM + tid] = f;
    }
  } else {
    if (tid < kM) sfr[tid] = 0.0f;
  }
  __syncthreads();
  if (tid < kH1) {
    float acc = p.pre_b0[tid];
#pragma unroll 8
    for (int m = 0; m < kM; ++m) acc = fmaf(p.w0t[m * kH1 + tid], sfr[m], acc);
    sh[tid] = fmaxf(acc, 0.0f);
  }
  __syncthreads();
  if (tid < kH2) {
    float a = p.pre_b1[tid];
#pragma unroll 8
    for (int k = 0; k < kH1; ++k) a = fmaf(p.w1t[k * kH2 + tid], sh[k], a);
    sp[tid] = fmaxf(a, 0.0f);
  }
  __syncthreads();
  if (tid < 64) {
    unsigned pk = (unsigned)f2bf(sp[2 * tid]) | ((unsigned)f2bf(sp[2 * tid + 1]) << 16);
    st32_coh((unsigned*)(dst + 512) + tid, pk);
  }
}

// ---- GRU phase (all 256 blocks, 512 threads = 8 waves) --------------------
// rt x bt tiles, 8-wave split-K, LDS reduce, in-block gate epilogue, optional
// proj-partial fusion. B operand (cross-XCD) preloaded to regs via sc1 loads;
// A (weights) plain loads -> L2-resident. bf16 state out: shfl-packed u64 sc1.
template<int NKS, int NB, int BROW>
__device__ __forceinline__ void gru_phase(
    float* red, float* sx,
    const unsigned short* __restrict__ Ar, const unsigned short* __restrict__ Az,
    const unsigned short* __restrict__ An,
    const unsigned short* __restrict__ Bsrc,
    const float* __restrict__ h_old,
    const float* __restrict__ bih, const float* __restrict__ bhh,
    const float* __restrict__ xin_f32,
    float* __restrict__ h_new_f32,
    unsigned short* __restrict__ h_bf16, int hStride, int hOff,
    unsigned short* __restrict__ x_bf16, int xStride,
    float* __restrict__ xout_f32,
    const float* __restrict__ pw, float* __restrict__ pproj) {
  int tid = threadIdx.x;
  int lane = tid & 63, w = tid >> 6, quad = lane >> 4;
  // XCD swizzle: each XCD owns 8 complete row tiles (all 4 bt of each).
  int xcd = blockIdx.x & 7, slot = blockIdx.x >> 3;
  int rt = xcd * 8 + (slot >> 2);
  int bt = slot & 3;
  int b = bt * 16 + (lane & 15);
  int s = (w * NKS) >> 3, e = ((w + 1) * NKS) >> 3;
  const unsigned long long* B64 = (const unsigned long long*)Bsrc;
  size_t bbase = ((size_t)b * BROW + quad) * 2;   // u64 units (frag = 2 x u64)
  const uint4* Arq = (const uint4*)Ar + (size_t)rt * NKS * 64 + lane;
  const uint4* Azq = (const uint4*)Az + (size_t)rt * NKS * 64 + lane;
  const uint4* Anq = (const uint4*)An + (size_t)rt * NKS * 64 + lane;
  // preload B fragments (cross-XCD -> sc1), statically indexed (no scratch)
  bf16x8 bv[8];
#pragma unroll
  for (int k = 0; k < 8; ++k) {
    int ks = s + k;
    if (ks < e) {
      size_t fi = bbase + (size_t)ks * 8;
      unsigned long long lo = ld64_coh(B64 + fi);
      unsigned long long hi = ld64_coh(B64 + fi + 1);
      uint4 u;
      u.x = (unsigned)lo; u.y = (unsigned)(lo >> 32);
      u.z = (unsigned)hi; u.w = (unsigned)(hi >> 32);
      bv[k] = asbf(u);
    }
  }
  f32x4 aR = {0.f, 0.f, 0.f, 0.f}, aZ = aR, aNI = aR, aNH = aR;
#pragma unroll
  for (int k = 0; k < 8; ++k) {
    int ks = s + k;
    if (ks < e) {
      aR = mfma16(asbf(Arq[ks * 64]), bv[k], aR);
      aZ = mfma16(asbf(Azq[ks * 64]), bv[k], aZ);
      if (ks < NB) aNI = mfma16(asbf(Anq[ks * 64]), bv[k], aNI);
      else         aNH = mfma16(asbf(Anq[ks * 64]), bv[k], aNH);
    }
  }
  *(f32x4*)(red + ((w * 4 + 0) * 64 + lane) * 4) = aR;
  *(f32x4*)(red + ((w * 4 + 1) * 64 + lane) * 4) = aZ;
  *(f32x4*)(red + ((w * 4 + 2) * 64 + lane) * 4) = aNI;
  *(f32x4*)(red + ((w * 4 + 3) * 64 + lane) * 4) = aNH;
  __syncthreads();
  if (w < 4) {
    int q = lane >> 4, bb = lane & 15;
    float R = 0.f, Z = 0.f, NI = 0.f, NH = 0.f;
#pragma unroll
    for (int ww = 0; ww < 8; ++ww) {
      int base = (ww * 4 * 64 + w * 16 + bb) * 4 + q;
      R  += red[base];
      Z  += red[base + 64 * 4];
      NI += red[base + 2 * 64 * 4];
      NH += red[base + 3 * 64 * 4];
    }
    int c = rt * 16 + w * 4 + q;
    float r = sigm(R + bih[c] + bhh[c]);
    float z = sigm(Z + bih[kC + c] + bhh[kC + c]);
    float n = tanh_(NI + bih[2 * kC + c] + r * (NH + bhh[2 * kC + c]));
    float hold = h_old[c * kB + b];
    float hn = (1.0f - z) * n + z * hold;
    h_new_f32[c * kB + b] = hn;                 // block-local: plain
    float xo = xin_f32 ? (xin_f32[c * kB + b] + hn) : hn;
    if (xout_f32) xout_f32[c * kB + b] = xo;    // block-local: plain
    if (pw) sx[(w * 4 + q) * 16 + bb] = xo;     // [c16][b16]
    // cross-XCD bf16 copies: gather q=0..3 into lanes<16, 8B sc1 store
    unsigned hbv = f2bf(hn);
    unsigned g0 = __shfl((int)hbv, bb);
    unsigned g1 = __shfl((int)hbv, bb + 16);
    unsigned g2 = __shfl((int)hbv, bb + 32);
    unsigned g3 = __shfl((int)hbv, bb + 48);
    if (lane < 16) {
      int c0 = rt * 16 + w * 4;
      st64_coh(&h_bf16[(size_t)b * hStride + hOff + c0], pack4(g0, g1, g2, g3));
    }
    if (x_bf16) {
      unsigned xbv = f2bf(xo);
      unsigned y0 = __shfl((int)xbv, bb);
      unsigned y1 = __shfl((int)xbv, bb + 16);
      unsigned y2 = __shfl((int)xbv, bb + 32);
      unsigned y3 = __shfl((int)xbv, bb + 48);
      if (lane < 16) {
        int c0 = rt * 16 + w * 4;
        st64_coh(&x_bf16[(size_t)b * xStride + c0], pack4(y0, y1, y2, y3));
      }
    }
  }
  if (pw) {
    __syncthreads();
    // proj partials: pproj[rt][m][bglobal] = proj_w[m, rt*16:+16] . xo[:, b]
    for (int idx = tid; idx < kM * 16; idx += 512) {
      int m = idx >> 4, bb = idx & 15;
      const float* wrow = pw + (size_t)m * kC + rt * 16;
      float a = 0.f;
#pragma unroll
      for (int c16 = 0; c16 < 16; ++c16) a += wrow[c16] * sx[c16 * 16 + bb];
      stf_coh(&pproj[((size_t)rt * kM + m) * kB + bt * 16 + bb], a);
    }
  }
}

// ---- the persistent kernel ------------------------------------------------
__global__ __launch_bounds__(512) void k_persist(KParams p) {
  __shared__ float red[8 * 4 * 64 * 4];   // 32 KB, reused by every phase
  __shared__ float sx[16 * 16];
  unsigned ep = 0;
  for (int t = 0; t < kT; ++t) {
    int cur = t & 1, nxt = cur ^ 1;
    if (blockIdx.x < kB) prenet_phase(p, t, red);
    gsync(p.bar, ++ep * 32);
    // attn GRU: B = xcat0[cur] (feat|p|h); h -> xcat0[nxt]+640, xcat1[cur] x-slot
    gru_phase<52, 20, 208>(red, sx, p.Aat0, p.Aat1, p.Aat2,
        p.xcat0 + (size_t)cur * X0, p.hA + (size_t)cur * HB,
        p.attn_bih, p.attn_bhh,
        nullptr, p.hA + (size_t)nxt * HB,
        p.xcat0 + (size_t)nxt * X0, 1664, 640,
        p.xcat1 + (size_t)cur * XC, 2048,
        nullptr, nullptr, nullptr);
    gsync(p.bar, ++ep * 32);
    // res GRU 1: B = xcat1[cur] (x|h1); h1 -> xcat1[nxt]+1024; x1 -> xcat2[cur]
    gru_phase<64, 32, 256>(red, sx, p.Ar00, p.Ar01, p.Ar02,
        p.xcat1 + (size_t)cur * XC, p.h1 + (size_t)cur * HB,
        p.g_bih0, p.g_bhh0,
        p.hA + (size_t)nxt * HB, p.h1 + (size_t)nxt * HB,
        p.xcat1 + (size_t)nxt * XC, 2048, 1024,
        p.xcat2 + (size_t)cur * XC, 2048,
        p.x1, nullptr, nullptr);
    gsync(p.bar, ++ep * 32);
    // res GRU 2 (+proj partials): B = xcat2[cur] (x1|h2); h2 -> xcat2[nxt]+1024
    gru_phase<64, 32, 256>(red, sx, p.Ar10, p.Ar11, p.Ar12,
        p.xcat2 + (size_t)cur * XC, p.h2 + (size_t)cur * HB,
        p.g_bih1, p.g_bhh1,
        p.x1, p.h2 + (size_t)nxt * HB,
        p.xcat2 + (size_t)nxt * XC, 2048, 1024,
        nullptr, 0,
        nullptr, p.proj_w, p.pproj);
    gsync(p.bar, ++ep * 32);
  }
  // finalize: frame t=511 from the last proj partials
  int idx = blockIdx.x * 512 + threadIdx.x;
  if (idx < kB * kM) {
    int b = idx / kM, m = idx % kM;
    float s = p.proj_b[m];
#pragma unroll 8
    for (int rt = 0; rt < 64; ++rt) s += ldf_coh(&p.pproj[((size_t)rt * kM + m) * kB + b]);
    p.out[(size_t)b * kT * kM + (size_t)(kT - 1) * kM + m] = s;
  }
}

} // namespace

extern "C" void kernel_launch(void* const* d_in, const int* in_sizes, int n_in,
                              void* d_out, int out_size, void* d_ws, size_t ws_size,
                              hipStream_t stream) {
  const float* inputs   = (const float*)d_in[0];
  const float* pre_w0   = (const float*)d_in[1];
  const float* pre_b0   = (const float*)d_in[2];
  const float* pre_w1   = (const float*)d_in[3];
  const float* pre_b1   = (const float*)d_in[4];
  const float* attn_wih = (const float*)d_in[5];
  const float* attn_whh = (const float*)d_in[6];
  const float* attn_bih = (const float*)d_in[7];
  const float* attn_bhh = (const float*)d_in[8];
  const float* gru_wih  = (const float*)d_in[9];
  const float* gru_whh  = (const float*)d_in[10];
  const float* gru_bih  = (const float*)d_in[11];
  const float* gru_bhh  = (const float*)d_in[12];
  const float* proj_w   = (const float*)d_in[13];
  const float* proj_b   = (const float*)d_in[14];
  float* out = (float*)d_out;
  char* ws = (char*)d_ws;

  const size_t ATTN_MAT = (size_t)64 * 52 * 64 * 8 * 2;  // 3,407,872 B
  const size_t RES_MAT  = (size_t)64 * 64 * 64 * 8 * 2;  // 4,194,304 B
  size_t off = 0;
  unsigned short* Aattn[3];
  for (int g = 0; g < 3; ++g) { Aattn[g] = (unsigned short*)(ws + off); off += ATTN_MAT; }
  unsigned short* Ares[2][3];
  for (int l = 0; l < 2; ++l)
    for (int g = 0; g < 3; ++g) { Ares[l][g] = (unsigned short*)(ws + off); off += RES_MAT; }
  float* w0t = (float*)(ws + off); off += (size_t)kM * kH1 * 4;
  float* w1t = (float*)(ws + off); off += (size_t)kH1 * kH2 * 4;
  float* pproj = (float*)(ws + off); off += (size_t)64 * kM * kB * 4;    // 1.25 MB
  size_t zeroBase = off;
  unsigned* bar = (unsigned*)(ws + off); off += 8 * 32 * 4;              // sharded ctrs
  unsigned short* xcat0 = (unsigned short*)(ws + off); off += 2 * (size_t)kB * 1664 * 2;
  unsigned short* xcat1 = (unsigned short*)(ws + off); off += 2 * (size_t)kB * 2048 * 2;
  unsigned short* xcat2 = (unsigned short*)(ws + off); off += 2 * (size_t)kB * 2048 * 2;
  float* hA = (float*)(ws + off); off += 2 * HB * 4;
  float* h1 = (float*)(ws + off); off += 2 * HB * 4;
  float* h2 = (float*)(ws + off); off += 2 * HB * 4;
  float* x1 = (float*)(ws + off); off += HB * 4;
  if (off > ws_size) return;  // fail loud if workspace too small

  // ---- one-time per launch: weight repack + transposes + zero init ----
  for (int g = 0; g < 3; ++g)
    k_build_frags<<<16 * 52, 256, 0, stream>>>(attn_wih, 640, attn_whh, kC,
                                               g * kC, 640, 52, 64, Aattn[g]);
  for (int l = 0; l < 2; ++l) {
    const float* wih = gru_wih + (size_t)l * 3 * kC * kC;
    const float* whh = gru_whh + (size_t)l * 3 * kC * kC;
    for (int g = 0; g < 3; ++g)
      k_build_frags<<<16 * 64, 256, 0, stream>>>(wih, kC, whh, kC,
                                                 g * kC, kC, 64, 64, Ares[l][g]);
  }
  k_transpose<<<(kH1 * kM + 255) / 256, 256, 0, stream>>>(pre_w0, kH1, kM, w0t);
  k_transpose<<<(kH2 * kH1 + 255) / 256, 256, 0, stream>>>(pre_w1, kH2, kH1, w1t);
  hipMemsetAsync(ws + zeroBase, 0, off - zeroBase, stream);

  // ---- the whole T loop in one cooperative launch ----
  KParams kp;
  kp.inputs = inputs; kp.proj_b = proj_b;
  kp.w0t = w0t; kp.pre_b0 = pre_b0; kp.w1t = w1t; kp.pre_b1 = pre_b1;
  kp.Aat0 = Aattn[0]; kp.Aat1 = Aattn[1]; kp.Aat2 = Aattn[2];
  kp.Ar00 = Ares[0][0]; kp.Ar01 = Ares[0][1]; kp.Ar02 = Ares[0][2];
  kp.Ar10 = Ares[1][0]; kp.Ar11 = Ares[1][1]; kp.Ar12 = Ares[1][2];
  kp.attn_bih = attn_bih; kp.attn_bhh = attn_bhh;
  kp.g_bih0 = gru_bih; kp.g_bhh0 = gru_bhh;
  kp.g_bih1 = gru_bih + 3 * kC; kp.g_bhh1 = gru_bhh + 3 * kC;
  kp.proj_w = proj_w;
  kp.xcat0 = xcat0; kp.xcat1 = xcat1; kp.xcat2 = xcat2;
  kp.hA = hA; kp.h1 = h1; kp.h2 = h2; kp.x1 = x1; kp.pproj = pproj; kp.out = out;
  kp.bar = bar;
  void* kargs[] = { (void*)&kp };
  (void)hipLaunchCooperativeKernel(reinterpret_cast<void*>(k_persist),
                                   dim3(256), dim3(512), kargs, 0, stream);
}

// Round 3
// 31128.217 us; speedup vs baseline: 2.6195x; 2.6195x over previous
//
#include <hip/hip_runtime.h>
#include <cstddef>

// Decoder: B=64, T=512, I=512, H1=256, H2=128, C=1024, M=80, L=2
// Round 8: persistent coop kernel, frag-major coherent state.
//   R7 post-mortem: B-operand read as scattered 8B sc1 loads -> one 64B
//   IF line-fill per 8B, latency-bound (~40us/phase). Fix: activation
//   panels stored in MFMA fragment order [bt][ks][lane][16B]; a wave's
//   B load for one ks = ONE contiguous 1KB dwordx4 sc0/sc1 load (8 issued
//   per wave in a single asm block, one internal vmcnt(0)). Epilogues
//   stage the 16x16 tile in LDS and write 32x16B frag stores. pproj
//   transposed to [b][m][rt] so prenet reduce streams 256B runs.
//   Barrier: relaxed add (sc1 write-through means vmcnt-drain at the
//   __syncthreads IS the release; no wbl2, no inv). Weights plain/L2.

namespace {

constexpr int kB = 64, kT = 512, kI = 512, kH1 = 256, kH2 = 128, kC = 1024, kM = 80;
constexpr size_t X0 = (size_t)kB * 1664;   // shorts; = 4 panels * 52ks * 512
constexpr size_t XC = (size_t)kB * 2048;   // shorts; = 4 panels * 64ks * 512
constexpr size_t HB = (size_t)kC * kB;

typedef __attribute__((ext_vector_type(8))) __bf16 bf16x8;
typedef __attribute__((ext_vector_type(4))) float f32x4;

__device__ __forceinline__ float sigm(float x) { return 1.0f / (1.0f + __expf(-x)); }
__device__ __forceinline__ float tanh_(float x) {
  float a = fabsf(x);
  float e = __expf(-2.0f * a);
  float r = (1.0f - e) / (1.0f + e);
  return copysignf(r, x);
}
__device__ __forceinline__ unsigned short f2bf(float x) {
  unsigned u = __builtin_bit_cast(unsigned, x);
  u += 0x7fffu + ((u >> 16) & 1u);   // RNE
  return (unsigned short)(u >> 16);
}
__device__ __forceinline__ bf16x8 asbf(uint4 v) { return __builtin_bit_cast(bf16x8, v); }
__device__ __forceinline__ f32x4 mfma16(bf16x8 a, bf16x8 b, f32x4 c) {
  return __builtin_amdgcn_mfma_f32_16x16x32_bf16(a, b, c, 0, 0, 0);
}

// ---- agent-scope (cross-XCD coherent) access helpers ----------------------
__device__ __forceinline__ unsigned long long ld64_coh(const void* p) {
  return __hip_atomic_load((unsigned long long*)p, __ATOMIC_RELAXED, __HIP_MEMORY_SCOPE_AGENT);
}
__device__ __forceinline__ void st64_coh(void* p, unsigned long long v) {
  __hip_atomic_store((unsigned long long*)p, v, __ATOMIC_RELAXED, __HIP_MEMORY_SCOPE_AGENT);
}
__device__ __forceinline__ void stf_coh(float* p, float v) {
  __hip_atomic_store(p, v, __ATOMIC_RELAXED, __HIP_MEMORY_SCOPE_AGENT);
}
__device__ __forceinline__ unsigned long long pack4(unsigned a, unsigned b,
                                                    unsigned c, unsigned d) {
  return (unsigned long long)(a & 0xffffu)
       | ((unsigned long long)(b & 0xffffu) << 16)
       | ((unsigned long long)(c & 0xffffu) << 32)
       | ((unsigned long long)(d & 0xffffu) << 48);
}
__device__ __forceinline__ unsigned long long packlds(const unsigned short* s,
                                                      int base, int bb) {
  return pack4(s[(base + 0) * 16 + bb], s[(base + 1) * 16 + bb],
               s[(base + 2) * 16 + bb], s[(base + 3) * 16 + bb]);
}

// ---- weight repack: fp32 [row][col] -> bf16 frag order [rt][ks][lane][8] ----
__global__ __launch_bounds__(256) void k_build_frags(
    const float* __restrict__ srcA, int ldA,
    const float* __restrict__ srcB, int ldB,
    int row0, int K1, int nks, int nrt, unsigned short* __restrict__ dst) {
  int idx = blockIdx.x * 256 + threadIdx.x;
  int lane = idx & 63;
  int ks = (idx >> 6) % nks;
  int rt = idx / (64 * nks);
  if (rt >= nrt) return;
  int row = row0 + rt * 16 + (lane & 15);
  int kk = ks * 32 + ((lane >> 4) & 3) * 8;
  const float* s = (kk < K1) ? (srcA + (size_t)row * ldA + kk)
                             : (srcB + (size_t)row * ldB + (kk - K1));
  unsigned short* d = dst + ((size_t)(rt * nks + ks) * 64 + lane) * 8;
#pragma unroll
  for (int j = 0; j < 8; ++j) d[j] = f2bf(s[j]);
}

__global__ __launch_bounds__(256) void k_transpose(const float* __restrict__ src,
    int R, int Ccols, float* __restrict__ dst) {
  int i = blockIdx.x * 256 + threadIdx.x;
  if (i >= R * Ccols) return;
  int r = i / Ccols, c = i % Ccols;
  dst[c * R + r] = src[r * Ccols + c];
}

// ---- persistent-kernel parameter block ------------------------------------
struct KParams {
  const float* inputs;
  const float* proj_b;
  const float* w0t;
  const float* pre_b0;
  const float* w1t;
  const float* pre_b1;
  const unsigned short* Aat0; const unsigned short* Aat1; const unsigned short* Aat2;
  const unsigned short* Ar00; const unsigned short* Ar01; const unsigned short* Ar02;
  const unsigned short* Ar10; const unsigned short* Ar11; const unsigned short* Ar12;
  const float* attn_bih; const float* attn_bhh;
  const float* g_bih0; const float* g_bhh0;
  const float* g_bih1; const float* g_bhh1;
  const float* proj_w;
  unsigned short* xcat0; unsigned short* xcat1; unsigned short* xcat2;
  float* hA; float* h1; float* h2; float* x1; float* pproj; float* out;
  unsigned* bar;   // 8 counters, 128B apart
};

// ---- grid barrier: per-XCD-sharded counters, relaxed (no cache maintenance)
// The compiler drains vmcnt(0) before s_barrier (syncthreads semantics), so
// all sc1 write-throughs have reached the coherence point before the add.
__device__ __forceinline__ void gsync(unsigned* bar, unsigned target) {
  __syncthreads();
  if (threadIdx.x == 0) {
    __hip_atomic_fetch_add(&bar[(blockIdx.x & 7) * 32], 1u,
                           __ATOMIC_RELAXED, __HIP_MEMORY_SCOPE_AGENT);
  }
  if (threadIdx.x < 8) {
    while (__hip_atomic_load(&bar[threadIdx.x * 32], __ATOMIC_RELAXED,
                             __HIP_MEMORY_SCOPE_AGENT) < target)
      __builtin_amdgcn_s_sleep(2);
  }
  __syncthreads();
}

// ---- prenet phase (blocks 0..63, 512 threads) -----------------------------
__device__ __forceinline__ void prenet_phase(const KParams& p, int t, float* smem) {
  float* sfr = smem;           // 80 (pad 96)
  float* sh  = smem + 96;      // 256
  float* sp  = smem + 384;     // 128
  int b = blockIdx.x, tid = threadIdx.x;
  int bt = b >> 4, bb = b & 15;
  const float* feat = p.inputs + ((size_t)b * kT + t) * kI;
  unsigned short* panel = p.xcat0 + (size_t)(t & 1) * X0 + (size_t)bt * 52 * 512;
  // feat -> frag panel: 64 chunks of 8 cols, one 16B frag-slot each
  if (tid < 64) {
    int col0 = tid * 8;
    float4 fa = *(const float4*)(feat + col0);
    float4 fb = *(const float4*)(feat + col0 + 4);
    unsigned long long lo = pack4(f2bf(fa.x), f2bf(fa.y), f2bf(fa.z), f2bf(fa.w));
    unsigned long long hi = pack4(f2bf(fb.x), f2bf(fb.y), f2bf(fb.z), f2bf(fb.w));
    int ks = col0 >> 5, quad = (col0 >> 3) & 3;
    unsigned short* dst = panel + ((size_t)ks * 64 + quad * 16 + bb) * 8;
    st64_coh(dst, lo);
    st64_coh(dst + 4, hi);
  }
  // frame reduce from pproj_t[b][m][rt] (64 contiguous floats per (b,m))
  if (tid >= 64 && tid < 64 + kM) {
    int m = tid - 64;
    if (t > 0) {
      const unsigned long long* pr =
          (const unsigned long long*)(p.pproj + ((size_t)b * kM + m) * 64);
      float s = 0.0f;
#pragma unroll
      for (int r = 0; r < 32; ++r) {
        float2 f = __builtin_bit_cast(float2, ld64_coh(pr + r));
        s += f.x + f.y;
      }
      float f = p.proj_b[m] + s;
      sfr[m] = f;
      p.out[(size_t)b * kT * kM + (size_t)(t - 1) * kM + m] = f;
    } else {
      sfr[m] = 0.0f;
    }
  }
  __syncthreads();
  if (tid < kH1) {
    float acc = p.pre_b0[tid];
#pragma unroll 8
    for (int m = 0; m < kM; ++m) acc = fmaf(p.w0t[m * kH1 + tid], sfr[m], acc);
    sh[tid] = fmaxf(acc, 0.0f);
  }
  __syncthreads();
  if (tid < kH2) {
    float a = p.pre_b1[tid];
#pragma unroll 8
    for (int k = 0; k < kH1; ++k) a = fmaf(p.w1t[k * kH2 + tid], sh[k], a);
    sp[tid] = fmaxf(a, 0.0f);
  }
  __syncthreads();
  // prenet out -> frag panel: cols 512..639 (16 chunks)
  if (tid < 16) {
    int col0 = 512 + tid * 8;
    const float* q = sp + tid * 8;
    unsigned long long lo = pack4(f2bf(q[0]), f2bf(q[1]), f2bf(q[2]), f2bf(q[3]));
    unsigned long long hi = pack4(f2bf(q[4]), f2bf(q[5]), f2bf(q[6]), f2bf(q[7]));
    int ks = col0 >> 5, quad = (col0 >> 3) & 3;
    unsigned short* dst = panel + ((size_t)ks * 64 + quad * 16 + bb) * 8;
    st64_coh(dst, lo);
    st64_coh(dst + 4, hi);
  }
}

// ---- GRU phase (all 256 blocks, 512 threads = 8 waves) --------------------
// rt x bt tiles, 8-wave split-K, LDS reduce, in-block gate epilogue, frag-
// order state panels. B: 8 coalesced 1KB dwordx4 sc0/sc1 loads per wave in
// ONE asm block (single internal vmcnt(0)). A (weights): plain, L2-resident.
template<int NKS, int NB>
__device__ __forceinline__ void gru_phase(
    float* red, float* sx, unsigned short* sxh, unsigned short* sxx,
    const unsigned short* __restrict__ Ar, const unsigned short* __restrict__ Az,
    const unsigned short* __restrict__ An,
    const unsigned short* __restrict__ Bpanels,   // + buf offset
    const float* __restrict__ h_old,
    const float* __restrict__ bih, const float* __restrict__ bhh,
    const float* __restrict__ xin_f32,
    float* __restrict__ h_new_f32,
    unsigned short* __restrict__ h_panels, int hNKS, int hOff,
    unsigned short* __restrict__ x_panels,        // nullable; 64ks, col off 0
    float* __restrict__ xout_f32,
    const float* __restrict__ pw, float* __restrict__ pproj) {
  int tid = threadIdx.x;
  int lane = tid & 63, w = tid >> 6;
  // XCD swizzle: each XCD owns 8 complete row tiles (all 4 bt of each).
  int xcd = blockIdx.x & 7, slot = blockIdx.x >> 3;
  int rt = xcd * 8 + (slot >> 2);
  int bt = slot & 3;
  int s = (w * NKS) >> 3, e = ((w + 1) * NKS) >> 3;
  const unsigned short* panel = Bpanels + (size_t)bt * NKS * 512;
  const unsigned short* pB = panel + (size_t)(s * 64 + lane) * 8;
  // ---- B preload: 8 coalesced 16B sc0/sc1 loads, one wait ----
  uint4 q0, q1, q2, q3, q4, q5, q6, q7;
  {
    const unsigned short* a0 = pB;
    const unsigned short* a1 = pB + 512;
    const unsigned short* a2 = pB + 2 * 512;
    const unsigned short* a3 = pB + 3 * 512;
    const unsigned short* a4 = pB + 4 * 512;
    const unsigned short* a5 = pB + 5 * 512;
    const unsigned short* a6 = pB + 6 * 512;
    const unsigned short* a7 = pB + 7 * 512;
    asm volatile(
        "global_load_dwordx4 %0, %8, off sc0 sc1\n\t"
        "global_load_dwordx4 %1, %9, off sc0 sc1\n\t"
        "global_load_dwordx4 %2, %10, off sc0 sc1\n\t"
        "global_load_dwordx4 %3, %11, off sc0 sc1\n\t"
        "global_load_dwordx4 %4, %12, off sc0 sc1\n\t"
        "global_load_dwordx4 %5, %13, off sc0 sc1\n\t"
        "global_load_dwordx4 %6, %14, off sc0 sc1\n\t"
        "global_load_dwordx4 %7, %15, off sc0 sc1\n\t"
        "s_waitcnt vmcnt(0)"
        : "=&v"(q0), "=&v"(q1), "=&v"(q2), "=&v"(q3),
          "=&v"(q4), "=&v"(q5), "=&v"(q6), "=&v"(q7)
        : "v"(a0), "v"(a1), "v"(a2), "v"(a3),
          "v"(a4), "v"(a5), "v"(a6), "v"(a7));
  }
  bf16x8 bv[8] = {asbf(q0), asbf(q1), asbf(q2), asbf(q3),
                  asbf(q4), asbf(q5), asbf(q6), asbf(q7)};
  const uint4* Arq = (const uint4*)Ar + (size_t)rt * NKS * 64 + lane;
  const uint4* Azq = (const uint4*)Az + (size_t)rt * NKS * 64 + lane;
  const uint4* Anq = (const uint4*)An + (size_t)rt * NKS * 64 + lane;
  f32x4 aR = {0.f, 0.f, 0.f, 0.f}, aZ = aR, aNI = aR, aNH = aR;
#pragma unroll
  for (int k = 0; k < 8; ++k) {
    int ks = s + k;
    if (NKS == 64 || ks < e) {
      aR = mfma16(asbf(Arq[(size_t)ks * 64]), bv[k], aR);
      aZ = mfma16(asbf(Azq[(size_t)ks * 64]), bv[k], aZ);
      if (ks < NB) aNI = mfma16(asbf(Anq[(size_t)ks * 64]), bv[k], aNI);
      else         aNH = mfma16(asbf(Anq[(size_t)ks * 64]), bv[k], aNH);
    }
  }
  *(f32x4*)(red + ((w * 4 + 0) * 64 + lane) * 4) = aR;
  *(f32x4*)(red + ((w * 4 + 1) * 64 + lane) * 4) = aZ;
  *(f32x4*)(red + ((w * 4 + 2) * 64 + lane) * 4) = aNI;
  *(f32x4*)(red + ((w * 4 + 3) * 64 + lane) * 4) = aNH;
  __syncthreads();
  if (w < 4) {
    int q = lane >> 4, bb = lane & 15;
    float R = 0.f, Z = 0.f, NI = 0.f, NH = 0.f;
#pragma unroll
    for (int ww = 0; ww < 8; ++ww) {
      int base = (ww * 4 * 64 + w * 16 + bb) * 4 + q;
      R  += red[base];
      Z  += red[base + 64 * 4];
      NI += red[base + 2 * 64 * 4];
      NH += red[base + 3 * 64 * 4];
    }
    int c = rt * 16 + w * 4 + q;
    int bcol = bt * 16 + bb;
    float r = sigm(R + bih[c] + bhh[c]);
    float z = sigm(Z + bih[kC + c] + bhh[kC + c]);
    float n = tanh_(NI + bih[2 * kC + c] + r * (NH + bhh[2 * kC + c]));
    float hold = h_old[c * kB + bcol];
    float hn = (1.0f - z) * n + z * hold;
    h_new_f32[c * kB + bcol] = hn;              // block-local: plain
    float xo = xin_f32 ? (xin_f32[c * kB + bcol] + hn) : hn;
    if (xout_f32) xout_f32[c * kB + bcol] = xo; // block-local: plain
    sxh[(w * 4 + q) * 16 + bb] = f2bf(hn);
    if (x_panels) sxx[(w * 4 + q) * 16 + bb] = f2bf(xo);
    if (pw) sx[(w * 4 + q) * 16 + bb] = xo;
  }
  __syncthreads();
  // h -> frag panel (cols hOff + rt*16 .. +16): 32 x 16B coherent stores
  if (tid < 32) {
    int bb = tid & 15, ch = tid >> 4;
    int col0 = hOff + rt * 16 + ch * 8;
    int ks = col0 >> 5, quad = (col0 >> 3) & 3;
    unsigned short* dst = h_panels + ((size_t)bt * hNKS + ks) * 512
                        + (size_t)(quad * 16 + bb) * 8;
    st64_coh(dst, packlds(sxh, ch * 8, bb));
    st64_coh(dst + 4, packlds(sxh, ch * 8 + 4, bb));
  } else if (x_panels && tid >= 64 && tid < 96) {
    int t2 = tid - 64, bb = t2 & 15, ch = t2 >> 4;
    int col0 = rt * 16 + ch * 8;
    int ks = col0 >> 5, quad = (col0 >> 3) & 3;
    unsigned short* dst = x_panels + ((size_t)bt * 64 + ks) * 512
                        + (size_t)(quad * 16 + bb) * 8;
    st64_coh(dst, packlds(sxx, ch * 8, bb));
    st64_coh(dst + 4, packlds(sxx, ch * 8 + 4, bb));
  }
  if (pw) {
    // proj partials: pproj_t[b][m][rt] = proj_w[m, rt*16:+16] . xo[:, b]
    for (int idx = tid; idx < kM * 16; idx += 512) {
      int m = idx >> 4, bb = idx & 15;
      const float* wrow = pw + (size_t)m * kC + rt * 16;
      float a = 0.f;
#pragma unroll
      for (int c16 = 0; c16 < 16; ++c16) a += wrow[c16] * sx[c16 * 16 + bb];
      stf_coh(&pproj[((size_t)(bt * 16 + bb) * kM + m) * 64 + rt], a);
    }
  }
}

// ---- the persistent kernel ------------------------------------------------
__global__ __launch_bounds__(512) void k_persist(KParams p) {
  __shared__ float red[8 * 4 * 64 * 4];      // 32 KB, reused by every phase
  __shared__ float sx[256];
  __shared__ unsigned short sxh[256];
  __shared__ unsigned short sxx[256];
  unsigned ep = 0;
  for (int t = 0; t < kT; ++t) {
    int cur = t & 1, nxt = cur ^ 1;
    if (blockIdx.x < kB) prenet_phase(p, t, red);
    gsync(p.bar, ++ep * 32);
    // attn GRU: B = xcat0[cur]; h -> xcat0[nxt] cols 640+, x -> xcat1[cur] cols 0+
    gru_phase<52, 20>(red, sx, sxh, sxx, p.Aat0, p.Aat1, p.Aat2,
        p.xcat0 + (size_t)cur * X0, p.hA + (size_t)cur * HB,
        p.attn_bih, p.attn_bhh,
        nullptr, p.hA + (size_t)nxt * HB,
        p.xcat0 + (size_t)nxt * X0, 52, 640,
        p.xcat1 + (size_t)cur * XC,
        nullptr, nullptr, nullptr);
    gsync(p.bar, ++ep * 32);
    // res GRU 1: B = xcat1[cur]; h1 -> xcat1[nxt] cols 1024+, x1 -> xcat2[cur]
    gru_phase<64, 32>(red, sx, sxh, sxx, p.Ar00, p.Ar01, p.Ar02,
        p.xcat1 + (size_t)cur * XC, p.h1 + (size_t)cur * HB,
        p.g_bih0, p.g_bhh0,
        p.hA + (size_t)nxt * HB, p.h1 + (size_t)nxt * HB,
        p.xcat1 + (size_t)nxt * XC, 64, 1024,
        p.xcat2 + (size_t)cur * XC,
        p.x1, nullptr, nullptr);
    gsync(p.bar, ++ep * 32);
    // res GRU 2 (+proj partials): B = xcat2[cur]; h2 -> xcat2[nxt] cols 1024+
    gru_phase<64, 32>(red, sx, sxh, sxx, p.Ar10, p.Ar11, p.Ar12,
        p.xcat2 + (size_t)cur * XC, p.h2 + (size_t)cur * HB,
        p.g_bih1, p.g_bhh1,
        p.x1, p.h2 + (size_t)nxt * HB,
        p.xcat2 + (size_t)nxt * XC, 64, 1024,
        nullptr,
        nullptr, p.proj_w, p.pproj);
    gsync(p.bar, ++ep * 32);
  }
  // finalize: frame t=511 from the last proj partials
  if (blockIdx.x < kB && threadIdx.x < kM) {
    int b = blockIdx.x, m = threadIdx.x;
    const unsigned long long* pr =
        (const unsigned long long*)(p.pproj + ((size_t)b * kM + m) * 64);
    float s = 0.0f;
#pragma unroll
    for (int r = 0; r < 32; ++r) {
      float2 f = __builtin_bit_cast(float2, ld64_coh(pr + r));
      s += f.x + f.y;
    }
    p.out[(size_t)b * kT * kM + (size_t)(kT - 1) * kM + m] = p.proj_b[m] + s;
  }
}

} // namespace

extern "C" void kernel_launch(void* const* d_in, const int* in_sizes, int n_in,
                              void* d_out, int out_size, void* d_ws, size_t ws_size,
                              hipStream_t stream) {
  const float* inputs   = (const float*)d_in[0];
  const float* pre_w0   = (const float*)d_in[1];
  const float* pre_b0   = (const float*)d_in[2];
  const float* pre_w1   = (const float*)d_in[3];
  const float* pre_b1   = (const float*)d_in[4];
  const float* attn_wih = (const float*)d_in[5];
  const float* attn_whh = (const float*)d_in[6];
  const float* attn_bih = (const float*)d_in[7];
  const float* attn_bhh = (const float*)d_in[8];
  const float* gru_wih  = (const float*)d_in[9];
  const float* gru_whh  = (const float*)d_in[10];
  const float* gru_bih  = (const float*)d_in[11];
  const float* gru_bhh  = (const float*)d_in[12];
  const float* proj_w   = (const float*)d_in[13];
  const float* proj_b   = (const float*)d_in[14];
  float* out = (float*)d_out;
  char* ws = (char*)d_ws;

  const size_t ATTN_MAT = (size_t)64 * 52 * 64 * 8 * 2;  // 3,407,872 B
  const size_t RES_MAT  = (size_t)64 * 64 * 64 * 8 * 2;  // 4,194,304 B
  size_t off = 0;
  unsigned short* Aattn[3];
  for (int g = 0; g < 3; ++g) { Aattn[g] = (unsigned short*)(ws + off); off += ATTN_MAT; }
  unsigned short* Ares[2][3];
  for (int l = 0; l < 2; ++l)
    for (int g = 0; g < 3; ++g) { Ares[l][g] = (unsigned short*)(ws + off); off += RES_MAT; }
  float* w0t = (float*)(ws + off); off += (size_t)kM * kH1 * 4;
  float* w1t = (float*)(ws + off); off += (size_t)kH1 * kH2 * 4;
  float* pproj = (float*)(ws + off); off += (size_t)kB * kM * 64 * 4;    // 1.25 MB
  size_t zeroBase = off;
  unsigned* bar = (unsigned*)(ws + off); off += 8 * 32 * 4;              // sharded ctrs
  unsigned short* xcat0 = (unsigned short*)(ws + off); off += 2 * X0 * 2;
  unsigned short* xcat1 = (unsigned short*)(ws + off); off += 2 * XC * 2;
  unsigned short* xcat2 = (unsigned short*)(ws + off); off += 2 * XC * 2;
  float* hA = (float*)(ws + off); off += 2 * HB * 4;
  float* h1 = (float*)(ws + off); off += 2 * HB * 4;
  float* h2 = (float*)(ws + off); off += 2 * HB * 4;
  float* x1 = (float*)(ws + off); off += HB * 4;
  if (off > ws_size) return;  // fail loud if workspace too small

  // ---- one-time per launch: weight repack + transposes + zero init ----
  for (int g = 0; g < 3; ++g)
    k_build_frags<<<16 * 52, 256, 0, stream>>>(attn_wih, 640, attn_whh, kC,
                                               g * kC, 640, 52, 64, Aattn[g]);
  for (int l = 0; l < 2; ++l) {
    const float* wih = gru_wih + (size_t)l * 3 * kC * kC;
    const float* whh = gru_whh + (size_t)l * 3 * kC * kC;
    for (int g = 0; g < 3; ++g)
      k_build_frags<<<16 * 64, 256, 0, stream>>>(wih, kC, whh, kC,
                                                 g * kC, kC, 64, 64, Ares[l][g]);
  }
  k_transpose<<<(kH1 * kM + 255) / 256, 256, 0, stream>>>(pre_w0, kH1, kM, w0t);
  k_transpose<<<(kH2 * kH1 + 255) / 256, 256, 0, stream>>>(pre_w1, kH2, kH1, w1t);
  hipMemsetAsync(ws + zeroBase, 0, off - zeroBase, stream);

  // ---- the whole T loop in one cooperative launch ----
  KParams kp;
  kp.inputs = inputs; kp.proj_b = proj_b;
  kp.w0t = w0t; kp.pre_b0 = pre_b0; kp.w1t = w1t; kp.pre_b1 = pre_b1;
  kp.Aat0 = Aattn[0]; kp.Aat1 = Aattn[1]; kp.Aat2 = Aattn[2];
  kp.Ar00 = Ares[0][0]; kp.Ar01 = Ares[0][1]; kp.Ar02 = Ares[0][2];
  kp.Ar10 = Ares[1][0]; kp.Ar11 = Ares[1][1]; kp.Ar12 = Ares[1][2];
  kp.attn_bih = attn_bih; kp.attn_bhh = attn_bhh;
  kp.g_bih0 = gru_bih; kp.g_bhh0 = gru_bhh;
  kp.g_bih1 = gru_bih + 3 * kC; kp.g_bhh1 = gru_bhh + 3 * kC;
  kp.proj_w = proj_w;
  kp.xcat0 = xcat0; kp.xcat1 = xcat1; kp.xcat2 = xcat2;
  kp.hA = hA; kp.h1 = h1; kp.h2 = h2; kp.x1 = x1; kp.pproj = pproj; kp.out = out;
  kp.bar = bar;
  void* kargs[] = { (void*)&kp };
  (void)hipLaunchCooperativeKernel(reinterpret_cast<void*>(k_persist),
                                   dim3(256), dim3(512), kargs, 0, stream);
}